// Round 11
// baseline (396.438 us; speedup 1.0000x reference)
//
#include <hip/hip_runtime.h>
#include <hip/hip_bf16.h>

#define NH   32
#define NKV  8
#define HD   128
#define SL   2048
#define HID  4096
#define KVW  1024   // NKV*HD
#define QKVN 6144   // HID + 2*KVW

typedef __attribute__((ext_vector_type(8))) short short8;
typedef __attribute__((ext_vector_type(4))) float f32x4;

static __device__ __forceinline__ unsigned short f2bf(float f){
  union { float f; unsigned int i; } v; v.f = f;
  unsigned int r = v.i + 0x7FFFu + ((v.i >> 16) & 1u);
  return (unsigned short)(r >> 16);
}
static __device__ __forceinline__ float bf2f(unsigned short u){
  union { unsigned int i; float f; } v; v.i = ((unsigned int)u) << 16; return v.f;
}
static __device__ __forceinline__ unsigned int pack2(float lo, float hi){
  return (unsigned int)f2bf(lo) | ((unsigned int)f2bf(hi) << 16);
}
static __device__ __forceinline__ unsigned int cvtpk(float lo, float hi){
  unsigned int d;
  asm("v_cvt_pk_bf16_f32 %0, %1, %2" : "=v"(d) : "v"(lo), "v"(hi));
  return d;
}

// async global -> LDS, 16 B per lane. LDS dest is wave-uniform base + lane*16;
// global source is per-lane.
static __device__ __forceinline__ void gload_lds16(const void* g, void* l){
  __builtin_amdgcn_global_load_lds(
      (const __attribute__((address_space(1))) void*)g,
      (__attribute__((address_space(3))) void*)l,
      16, 0, 0);
}

// ---------------- cast fp32 -> bf16, 8 elems/thread (measured ~6.4 TB/s, BW-bound) ----------------
__global__ void cast_f32_bf16(const float* __restrict__ src, uint4* __restrict__ dst, int n8){
  int stride = gridDim.x * blockDim.x;
  for (int i = blockIdx.x * blockDim.x + threadIdx.x; i < n8; i += stride){
    float4 a = ((const float4*)src)[2*i + 0];
    float4 b = ((const float4*)src)[2*i + 1];
    uint4 o;
    o.x = pack2(a.x, a.y); o.y = pack2(a.z, a.w);
    o.z = pack2(b.x, b.y); o.w = pack2(b.z, b.w);
    dst[i] = o;
  }
}

// ---------------- RoPE cos/sin table ----------------
__global__ void rope_table_kernel(const int* __restrict__ pos, float2* __restrict__ tab){
  int i = blockIdx.x * blockDim.x + threadIdx.x;
  if (i >= SL * 64) return;
  int s = i >> 6, f = i & 63;
  float inv = expf(-((float)(2 * f) / 128.0f) * 9.210340371976184f);
  float ang = (float)pos[s] * inv;
  float sn, cs;
  sincosf(ang, &sn, &cs);
  tab[i] = make_float2(cs, sn);
}

// ---------------- in-place RoPE, vectorized: thread = 8 (f, f+64) pairs ----------------
__global__ void rope_apply_kernel(unsigned short* x, const float2* __restrict__ tab,
                                  int nheads, int rowstride){
  int i = blockIdx.x * blockDim.x + threadIdx.x;
  int total = SL * nheads * 8;
  if (i >= total) return;
  int fb = (i & 7) * 8;            // f0 of this thread's 8 pairs
  int t = i >> 3;
  int h = t % nheads;
  int s = t / nheads;
  size_t base = (size_t)s * rowstride + h * HD;
  short8 x1 = *(const short8*)&x[base + fb];
  short8 x2 = *(const short8*)&x[base + fb + 64];
  const float2* tb = &tab[s * 64 + fb];
  short8 o1, o2;
#pragma unroll
  for (int j = 0; j < 8; ++j){
    float2 cs = tb[j];
    float a = bf2f((unsigned short)x1[j]);
    float b = bf2f((unsigned short)x2[j]);
    o1[j] = (short)f2bf(a * cs.x - b * cs.y);
    o2[j] = (short)f2bf(b * cs.x + a * cs.y);
  }
  *(short8*)&x[base + fb]      = o1;
  *(short8*)&x[base + fb + 64] = o2;
}

// ========== bt-GEMM: C[M][N] = A[M][K] * B[N][K]^T ==========
template<int BN, bool F32OUT>
__global__ __launch_bounds__(256) void gemm_bt(
  const unsigned short* __restrict__ A,
  const unsigned short* __restrict__ B,
  void* __restrict__ Cp, int M, int N, int K)
{
  constexpr int NFR = BN / 32;
  __shared__ __align__(16) unsigned short As[2][128 * 32];
  __shared__ __align__(16) unsigned short Bs[2][BN * 32];
  const int tid = threadIdx.x;
  const int lane = tid & 63, wid = tid >> 6;
  const int g = lane >> 4, c15 = lane & 15;
  const int wr = wid >> 1, wc = wid & 1;

  const int gx = gridDim.x, gy = gridDim.y;
  const int nwg = gx * gy;
  const int lin = blockIdx.y * gx + blockIdx.x;
  int mb, nb;
  const int cpx = nwg >> 3;
  const int RN  = cpx >> 3;
  if (RN > 0 && (gy & 7) == 0 && (cpx & 7) == 0 && gx % RN == 0 && (8 % (gx / RN)) == 0){
    int xcd = lin & 7, j = lin >> 3;
    int nrc = gx / RN;
    int rr = xcd / nrc, rc = xcd % nrc;
    mb = rr * 8 + (j & 7);
    nb = rc * RN + (j >> 3);
  } else { mb = lin / gx; nb = lin % gx; }
  const int m0 = mb * 128, n0 = nb * BN;

  const int srowA = wid * 32 + (lane >> 2);
  const int srowB = wid * (BN / 4) + (lane >> 2);
  const int scol  = (lane & 3) * 8;
  const unsigned short* Ag = &A[(size_t)(m0 + srowA) * K + scol];
  const unsigned short* Bg = &B[(size_t)(n0 + srowB) * K + scol];
  const size_t K16 = (size_t)16 * K;

  f32x4 acc[4][NFR] = {};

  gload_lds16(Ag,       &As[0][wid * 1024]);
  gload_lds16(Ag + K16, &As[0][wid * 1024 + 512]);
#pragma unroll
  for (int q = 0; q < BN / 64; ++q)
    gload_lds16(Bg + q * K16, &Bs[0][wid * (BN / 4) * 32 + q * 512]);
  __syncthreads();

  const int nk = K >> 5;
  for (int t = 0; t < nk; ++t){
    const int cur = t & 1;
    if (t + 1 < nk){
      const unsigned short* a2 = Ag + (size_t)(t + 1) * 32;
      const unsigned short* b2 = Bg + (size_t)(t + 1) * 32;
      const int nb2 = cur ^ 1;
      gload_lds16(a2,       &As[nb2][wid * 1024]);
      gload_lds16(a2 + K16, &As[nb2][wid * 1024 + 512]);
#pragma unroll
      for (int q = 0; q < BN / 64; ++q)
        gload_lds16(b2 + q * K16, &Bs[nb2][wid * (BN / 4) * 32 + q * 512]);
    }
    short8 af[4], bfr[NFR];
#pragma unroll
    for (int m = 0; m < 4; ++m)
      af[m] = *(const short8*)(&As[cur][(wr * 64 + m * 16 + c15) * 32 + g * 8]);
#pragma unroll
    for (int n = 0; n < NFR; ++n)
      bfr[n] = *(const short8*)(&Bs[cur][(wc * (BN / 2) + n * 16 + c15) * 32 + g * 8]);
#pragma unroll
    for (int m = 0; m < 4; ++m)
#pragma unroll
      for (int n = 0; n < NFR; ++n)
        acc[m][n] = __builtin_amdgcn_mfma_f32_16x16x32_bf16(af[m], bfr[n], acc[m][n], 0, 0, 0);
    __syncthreads();
  }

#pragma unroll
  for (int m = 0; m < 4; ++m)
#pragma unroll
    for (int n = 0; n < NFR; ++n){
      int row = m0 + wr * 64 + m * 16 + g * 4;
      int col = n0 + wc * (BN / 2) + n * 16 + c15;
      f32x4 v = acc[m][n];
      if (F32OUT){
        float* C = (float*)Cp;
#pragma unroll
        for (int r = 0; r < 4; ++r) C[(size_t)(row + r) * N + col] = v[r];
      } else {
        unsigned short* C = (unsigned short*)Cp;
#pragma unroll
        for (int r = 0; r < 4; ++r) C[(size_t)(row + r) * N + col] = f2bf(v[r]);
      }
    }
}

// ---------------- V transpose: v[s][h*128+d] (stride vstride) -> vt[h][d][s] ----------------
__global__ void transpose_v_kernel(const unsigned short* __restrict__ v, int vstride,
                                   unsigned short* __restrict__ vt){
  __shared__ unsigned short t[64][65];
  int h  = blockIdx.z;
  int d0 = blockIdx.y * 64;
  int s0 = blockIdx.x * 64;
  int c  = threadIdx.x & 63;
  int r0 = threadIdx.x >> 6;
#pragma unroll
  for (int r = r0; r < 64; r += 4) t[r][c] = v[(size_t)(s0 + r) * vstride + h * HD + d0 + c];
  __syncthreads();
#pragma unroll
  for (int r = r0; r < 64; r += 4) vt[(size_t)(h * HD + d0 + r) * SL + s0 + c] = t[c][r];
}

// ---------------- flash attention v2: 4 waves, 32 q-rows/wave, shared K/V reads ----------------
// LDS-BW fix: bk/bv read ONCE per wave, used for BOTH q-halves -> LDS bytes per
// unit work halved vs 8-wave version. Double-buffered K/V; one barrier/iter.
__global__ __launch_bounds__(256, 2) void flash_attn_kernel(
  const unsigned short* __restrict__ Q,    // row stride QKVN
  const unsigned short* __restrict__ Kb,   // row stride QKVN
  const unsigned short* __restrict__ Vt,   // [kvh*128+d][SL]
  unsigned short* __restrict__ O)          // row stride HID
{
  __shared__ __align__(16) unsigned short Ks[2][64 * 128];   // XOR-swizzled, 256B rows
  __shared__ __align__(16) unsigned short Vs[2][128 * 64];   // XOR-swizzled, 128B rows
  const int tid = threadIdx.x, lane = tid & 63, wid = tid >> 6;  // 4 waves
  const int g = lane >> 4, c15 = lane & 15;
  const int kvh = blockIdx.x;
  const int yy = blockIdx.y;
  const int qb = (yy < 32) ? (63 - yy) : (yy - 32);   // heavy-first, pair-balanced
  const int h = kvh * 4 + wid;            // one head per wave
  const int q0 = qb * 32;

  // Q frags for both q-halves: col=c15 -> q, k = kk*32 + g*8 + j
  short8 aq[2][4];
#pragma unroll
  for (int qh = 0; qh < 2; ++qh){
    size_t qrow = (size_t)(q0 + qh * 16 + c15) * QKVN + h * HD;
#pragma unroll
    for (int kk = 0; kk < 4; ++kk)
      aq[qh][kk] = *(const short8*)(&Q[qrow + kk * 32 + g * 8]);
  }

  // staging: K 64r x 128c (4 thr/row, 4 slots each), V 128r x 64c (2 thr/row, 4 slots)
  const int krow = tid >> 2;
  const int vrow = tid >> 1;
  const unsigned short* Kgb = Kb + (size_t)kvh * HD;
  const unsigned short* Vgb = Vt + ((size_t)kvh * HD + vrow) * SL;

  uint4 kr[4], vr[4];
  auto loadKV = [&](int kt){
    const unsigned short* kg = Kgb + (size_t)(kt * 64 + krow) * QKVN;
    const unsigned short* vg = Vgb + kt * 64;
#pragma unroll
    for (int j = 0; j < 4; ++j){
      kr[j] = *(const uint4*)(kg + ((tid & 3) * 4 + j) * 8);
      vr[j] = *(const uint4*)(vg + ((tid & 1) * 4 + j) * 8);
    }
  };
  auto writeKV = [&](int buf){
#pragma unroll
    for (int j = 0; j < 4; ++j){
      int ks = (tid & 3) * 4 + j;
      int vs = (tid & 1) * 4 + j;
      *(uint4*)((char*)&Ks[buf][0] + krow * 256 + ((ks * 16) ^ ((krow & 7) << 4))) = kr[j];
      *(uint4*)((char*)&Vs[buf][0] + vrow * 128 + ((vs * 16) ^ ((vrow & 7) << 4))) = vr[j];
    }
  };

  float m_i[2] = {-1e30f, -1e30f}, l_i[2] = {0.f, 0.f};
  f32x4 oacc[2][8];
#pragma unroll
  for (int qh = 0; qh < 2; ++qh)
#pragma unroll
    for (int df = 0; df < 8; ++df) oacc[qh][df] = (f32x4){0.f, 0.f, 0.f, 0.f};

  const float scl2 = 0.08838834764831845f * 1.4426950408889634f;  // 1/sqrt(128)*log2e
  const int nt = (q0 + 31) / 64 + 1;

  loadKV(0);
  writeKV(0);
  if (nt > 1) loadKV(1);
  __syncthreads();

  for (int kt = 0; kt < nt; ++kt){
    const int cur = kt & 1, nxt = cur ^ 1;
    if (kt + 1 < nt) writeKV(nxt);
    if (kt + 2 < nt) loadKV(kt + 2);

    // S^T = K Q, both q-halves share each bk read
    f32x4 sc[2][4];
#pragma unroll
    for (int qh = 0; qh < 2; ++qh)
#pragma unroll
      for (int f = 0; f < 4; ++f) sc[qh][f] = (f32x4){0.f, 0.f, 0.f, 0.f};
    __builtin_amdgcn_s_setprio(1);
#pragma unroll
    for (int f = 0; f < 4; ++f)
#pragma unroll
      for (int kk = 0; kk < 4; ++kk){
        short8 bk = *(const short8*)((const char*)&Ks[cur][0] + (f * 16 + c15) * 256 +
                                     ((kk * 64 + g * 16) ^ ((c15 & 7) << 4)));
        sc[0][f] = __builtin_amdgcn_mfma_f32_16x16x32_bf16(bk, aq[0][kk], sc[0][f], 0, 0, 0);
        sc[1][f] = __builtin_amdgcn_mfma_f32_16x16x32_bf16(bk, aq[1][kk], sc[1][f], 0, 0, 0);
      }
    __builtin_amdgcn_s_setprio(0);

    // per-q-half softmax
    float p[2][4][4];
    unsigned int pd[2][4][2];
#pragma unroll
    for (int qh = 0; qh < 2; ++qh){
      const int qg = q0 + qh * 16 + c15;
      if (kt * 64 + 63 <= q0 + qh * 16){   // wave-uniformly full tile
#pragma unroll
        for (int f = 0; f < 4; ++f)
#pragma unroll
          for (int r = 0; r < 4; ++r) p[qh][f][r] = sc[qh][f][r] * scl2;
      } else {
#pragma unroll
        for (int f = 0; f < 4; ++f)
#pragma unroll
          for (int r = 0; r < 4; ++r){
            int kvg = kt * 64 + f * 16 + g * 4 + r;
            p[qh][f][r] = (kvg <= qg) ? sc[qh][f][r] * scl2 : -1e30f;
          }
      }

      float pmax = p[qh][0][0];
#pragma unroll
      for (int f = 0; f < 4; ++f)
#pragma unroll
        for (int r = 0; r < 4; ++r) pmax = fmaxf(pmax, p[qh][f][r]);
      pmax = fmaxf(pmax, __shfl_xor(pmax, 16, 64));
      pmax = fmaxf(pmax, __shfl_xor(pmax, 32, 64));

      if (!__all(pmax - m_i[qh] <= 8.0f)){
        float mnew = fmaxf(m_i[qh], pmax);
        float cf = exp2f(m_i[qh] - mnew);
        float cfr[4];
#pragma unroll
        for (int r = 0; r < 4; ++r) cfr[r] = __shfl(cf, (lane & 48) | (g * 4 + r), 64);
#pragma unroll
        for (int df = 0; df < 8; ++df)
#pragma unroll
          for (int r = 0; r < 4; ++r) oacc[qh][df][r] *= cfr[r];
        l_i[qh] *= cf;
        m_i[qh] = mnew;
      }

      float lsum = 0.f;
#pragma unroll
      for (int f = 0; f < 4; ++f)
#pragma unroll
        for (int r = 0; r < 4; ++r){
          float e = exp2f(p[qh][f][r] - m_i[qh]); p[qh][f][r] = e; lsum += e;
        }
      lsum += __shfl_xor(lsum, 16, 64);
      lsum += __shfl_xor(lsum, 32, 64);
      l_i[qh] += lsum;

#pragma unroll
      for (int f = 0; f < 4; ++f){
        pd[qh][f][0] = cvtpk(p[qh][f][0], p[qh][f][1]);
        pd[qh][f][1] = cvtpk(p[qh][f][2], p[qh][f][3]);
      }
    }

    // PV: each bv read once, used by both q-halves
    const int src0 = ((g & 1) << 5) | c15;
    const int src1 = src0 + 16;
    const bool hiF = (g >= 2);
#pragma unroll
    for (int kk = 0; kk < 2; ++kk){
      union { unsigned int u[4]; short8 s8; } pa[2];
#pragma unroll
      for (int qh = 0; qh < 2; ++qh)
#pragma unroll
        for (int pr = 0; pr < 2; ++pr){
          unsigned int a0 = __shfl((int)pd[qh][2 * kk + 0][pr], src0, 64);
          unsigned int b0 = __shfl((int)pd[qh][2 * kk + 1][pr], src0, 64);
          unsigned int a1 = __shfl((int)pd[qh][2 * kk + 0][pr], src1, 64);
          unsigned int b1 = __shfl((int)pd[qh][2 * kk + 1][pr], src1, 64);
          pa[qh].u[pr]     = hiF ? b0 : a0;
          pa[qh].u[2 + pr] = hiF ? b1 : a1;
        }
      __builtin_amdgcn_s_setprio(1);
#pragma unroll
      for (int df = 0; df < 8; ++df){
        short8 bv = *(const short8*)((const char*)&Vs[cur][0] + (df * 16 + c15) * 128 +
                                     ((kk * 64 + g * 16) ^ ((c15 & 7) << 4)));
        oacc[0][df] = __builtin_amdgcn_mfma_f32_16x16x32_bf16(pa[0].s8, bv, oacc[0][df], 0, 0, 0);
        oacc[1][df] = __builtin_amdgcn_mfma_f32_16x16x32_bf16(pa[1].s8, bv, oacc[1][df], 0, 0, 0);
      }
      __builtin_amdgcn_s_setprio(0);
    }
    __syncthreads();   // publish buf[nxt], release buf[cur]
  }

  // epilogue: per q-half divide by l and store
#pragma unroll
  for (int qh = 0; qh < 2; ++qh){
    float lr[4];
#pragma unroll
    for (int r = 0; r < 4; ++r) lr[r] = __shfl(l_i[qh], (lane & 48) | (g * 4 + r), 64);
#pragma unroll
    for (int df = 0; df < 8; ++df)
#pragma unroll
      for (int r = 0; r < 4; ++r){
        int row = q0 + qh * 16 + g * 4 + r;
        O[(size_t)row * HID + h * HD + df * 16 + c15] = f2bf(oacc[qh][df][r] / lr[r]);
      }
  }
}

extern "C" void kernel_launch(void* const* d_in, const int* in_sizes, int n_in,
                              void* d_out, int out_size, void* d_ws, size_t ws_size,
                              hipStream_t stream)
{
  const float* hs  = (const float*)d_in[0];
  const float* qw  = (const float*)d_in[1];
  const float* kw  = (const float*)d_in[2];
  const float* vw  = (const float*)d_in[3];
  const float* ow  = (const float*)d_in[4];
  const int*   pos = (const int*)d_in[5];

  char* w = (char*)d_ws;
  auto alloc = [&](size_t bytes){ char* p = w; w += (bytes + 255) & ~(size_t)255; return p; };
  unsigned short* xb   = (unsigned short*)alloc((size_t)SL * HID * 2);
  unsigned short* wqkv = (unsigned short*)alloc((size_t)QKVN * HID * 2);
  unsigned short* owb  = (unsigned short*)alloc((size_t)HID * HID * 2);
  unsigned short* qkv  = (unsigned short*)alloc((size_t)SL * QKVN * 2);
  unsigned short* vt   = (unsigned short*)alloc((size_t)SL * KVW * 2);
  unsigned short* ab   = (unsigned short*)alloc((size_t)SL * HID * 2);
  float2*         tab  = (float2*)alloc((size_t)SL * 64 * sizeof(float2));

  auto cast = [&](const float* s, unsigned short* d, long n){
    int n8 = (int)(n / 8);
    int blocks = (n8 + 255) / 256; if (blocks > 2048) blocks = 2048;
    cast_f32_bf16<<<blocks, 256, 0, stream>>>(s, (uint4*)d, n8);
  };
  cast(hs, xb, (long)SL * HID);
  cast(qw, wqkv,                              (long)HID * HID);
  cast(kw, wqkv + (size_t)HID * HID,          (long)KVW * HID);
  cast(vw, wqkv + (size_t)(HID + KVW) * HID,  (long)KVW * HID);
  cast(ow, owb,                               (long)HID * HID);

  rope_table_kernel<<<(SL * 64 + 255) / 256, 256, 0, stream>>>(pos, tab);

  // fused QKV projection: [2048][6144] = xb @ wqkv^T  (grid 48x16 = 768 = 3/CU)
  gemm_bt<128, false><<<dim3(QKVN / 128, SL / 128), 256, 0, stream>>>(xb, wqkv, qkv, SL, QKVN, HID);

  // RoPE on q+k heads (40 heads), vectorized 8 pairs/thread
  rope_apply_kernel<<<(SL * 40 * 8 + 255) / 256, 256, 0, stream>>>(qkv, tab, 40, QKVN);

  transpose_v_kernel<<<dim3(SL / 64, HD / 64, NKV), 256, 0, stream>>>(qkv + HID + KVW, QKVN, vt);

  // grid: 8 KV groups x 64 q-blocks of 32 rows; 256-thread blocks (4 waves)
  flash_attn_kernel<<<dim3(NKV, SL / 32), 256, 0, stream>>>(qkv, qkv + HID, vt, ab);

  // O projection: proven 128x128 engine (grid 32x16 = 512)
  gemm_bt<128, true><<<dim3(HID / 128, SL / 128), 256, 0, stream>>>(ab, owb, d_out, SL, HID, HID);
}

// Round 12
// 389.316 us; speedup vs baseline: 1.0183x; 1.0183x over previous
//
#include <hip/hip_runtime.h>
#include <hip/hip_bf16.h>

#define NH   32
#define NKV  8
#define HD   128
#define SL   2048
#define HID  4096
#define KVW  1024   // NKV*HD
#define QKVN 6144   // HID + 2*KVW

typedef __attribute__((ext_vector_type(8))) short short8;
typedef __attribute__((ext_vector_type(4))) float f32x4;

static __device__ __forceinline__ unsigned short f2bf(float f){
  union { float f; unsigned int i; } v; v.f = f;
  unsigned int r = v.i + 0x7FFFu + ((v.i >> 16) & 1u);
  return (unsigned short)(r >> 16);
}
static __device__ __forceinline__ float bf2f(unsigned short u){
  union { unsigned int i; float f; } v; v.i = ((unsigned int)u) << 16; return v.f;
}
static __device__ __forceinline__ unsigned int pack2(float lo, float hi){
  return (unsigned int)f2bf(lo) | ((unsigned int)f2bf(hi) << 16);
}
static __device__ __forceinline__ unsigned int cvtpk(float lo, float hi){
  unsigned int d;
  asm("v_cvt_pk_bf16_f32 %0, %1, %2" : "=v"(d) : "v"(lo), "v"(hi));
  return d;
}

// async global -> LDS, 16 B per lane. LDS dest is wave-uniform base + lane*16;
// global source is per-lane (enables pre-swizzled sources).
static __device__ __forceinline__ void gload_lds16(const void* g, void* l){
  __builtin_amdgcn_global_load_lds(
      (const __attribute__((address_space(1))) void*)g,
      (__attribute__((address_space(3))) void*)l,
      16, 0, 0);
}

// ---------------- cast fp32 -> bf16, 8 elems/thread (measured ~6.4 TB/s, BW-bound) ----------------
__global__ void cast_f32_bf16(const float* __restrict__ src, uint4* __restrict__ dst, int n8){
  int stride = gridDim.x * blockDim.x;
  for (int i = blockIdx.x * blockDim.x + threadIdx.x; i < n8; i += stride){
    float4 a = ((const float4*)src)[2*i + 0];
    float4 b = ((const float4*)src)[2*i + 1];
    uint4 o;
    o.x = pack2(a.x, a.y); o.y = pack2(a.z, a.w);
    o.z = pack2(b.x, b.y); o.w = pack2(b.z, b.w);
    dst[i] = o;
  }
}

// ---------------- RoPE cos/sin table ----------------
__global__ void rope_table_kernel(const int* __restrict__ pos, float2* __restrict__ tab){
  int i = blockIdx.x * blockDim.x + threadIdx.x;
  if (i >= SL * 64) return;
  int s = i >> 6, f = i & 63;
  float inv = expf(-((float)(2 * f) / 128.0f) * 9.210340371976184f);
  float ang = (float)pos[s] * inv;
  float sn, cs;
  sincosf(ang, &sn, &cs);
  tab[i] = make_float2(cs, sn);
}

// ---------------- in-place RoPE, vectorized: thread = 8 (f, f+64) pairs ----------------
__global__ void rope_apply_kernel(unsigned short* x, const float2* __restrict__ tab,
                                  int nheads, int rowstride){
  int i = blockIdx.x * blockDim.x + threadIdx.x;
  int total = SL * nheads * 8;
  if (i >= total) return;
  int fb = (i & 7) * 8;
  int t = i >> 3;
  int h = t % nheads;
  int s = t / nheads;
  size_t base = (size_t)s * rowstride + h * HD;
  short8 x1 = *(const short8*)&x[base + fb];
  short8 x2 = *(const short8*)&x[base + fb + 64];
  const float2* tb = &tab[s * 64 + fb];
  short8 o1, o2;
#pragma unroll
  for (int j = 0; j < 8; ++j){
    float2 cs = tb[j];
    float a = bf2f((unsigned short)x1[j]);
    float b = bf2f((unsigned short)x2[j]);
    o1[j] = (short)f2bf(a * cs.x - b * cs.y);
    o2[j] = (short)f2bf(b * cs.x + a * cs.y);
  }
  *(short8*)&x[base + fb]      = o1;
  *(short8*)&x[base + fb + 64] = o2;
}

// ========== bt-GEMM: C[M][N] = A[M][K] * B[N][K]^T ==========
template<int BN, bool F32OUT>
__global__ __launch_bounds__(256) void gemm_bt(
  const unsigned short* __restrict__ A,
  const unsigned short* __restrict__ B,
  void* __restrict__ Cp, int M, int N, int K)
{
  constexpr int NFR = BN / 32;
  __shared__ __align__(16) unsigned short As[2][128 * 32];
  __shared__ __align__(16) unsigned short Bs[2][BN * 32];
  const int tid = threadIdx.x;
  const int lane = tid & 63, wid = tid >> 6;
  const int g = lane >> 4, c15 = lane & 15;
  const int wr = wid >> 1, wc = wid & 1;

  const int gx = gridDim.x, gy = gridDim.y;
  const int nwg = gx * gy;
  const int lin = blockIdx.y * gx + blockIdx.x;
  int mb, nb;
  const int cpx = nwg >> 3;
  const int RN  = cpx >> 3;
  if (RN > 0 && (gy & 7) == 0 && (cpx & 7) == 0 && gx % RN == 0 && (8 % (gx / RN)) == 0){
    int xcd = lin & 7, j = lin >> 3;
    int nrc = gx / RN;
    int rr = xcd / nrc, rc = xcd % nrc;
    mb = rr * 8 + (j & 7);
    nb = rc * RN + (j >> 3);
  } else { mb = lin / gx; nb = lin % gx; }
  const int m0 = mb * 128, n0 = nb * BN;

  const int srowA = wid * 32 + (lane >> 2);
  const int srowB = wid * (BN / 4) + (lane >> 2);
  const int scol  = (lane & 3) * 8;
  const unsigned short* Ag = &A[(size_t)(m0 + srowA) * K + scol];
  const unsigned short* Bg = &B[(size_t)(n0 + srowB) * K + scol];
  const size_t K16 = (size_t)16 * K;

  f32x4 acc[4][NFR] = {};

  gload_lds16(Ag,       &As[0][wid * 1024]);
  gload_lds16(Ag + K16, &As[0][wid * 1024 + 512]);
#pragma unroll
  for (int q = 0; q < BN / 64; ++q)
    gload_lds16(Bg + q * K16, &Bs[0][wid * (BN / 4) * 32 + q * 512]);
  __syncthreads();

  const int nk = K >> 5;
  for (int t = 0; t < nk; ++t){
    const int cur = t & 1;
    if (t + 1 < nk){
      const unsigned short* a2 = Ag + (size_t)(t + 1) * 32;
      const unsigned short* b2 = Bg + (size_t)(t + 1) * 32;
      const int nb2 = cur ^ 1;
      gload_lds16(a2,       &As[nb2][wid * 1024]);
      gload_lds16(a2 + K16, &As[nb2][wid * 1024 + 512]);
#pragma unroll
      for (int q = 0; q < BN / 64; ++q)
        gload_lds16(b2 + q * K16, &Bs[nb2][wid * (BN / 4) * 32 + q * 512]);
    }
    short8 af[4], bfr[NFR];
#pragma unroll
    for (int m = 0; m < 4; ++m)
      af[m] = *(const short8*)(&As[cur][(wr * 64 + m * 16 + c15) * 32 + g * 8]);
#pragma unroll
    for (int n = 0; n < NFR; ++n)
      bfr[n] = *(const short8*)(&Bs[cur][(wc * (BN / 2) + n * 16 + c15) * 32 + g * 8]);
#pragma unroll
    for (int m = 0; m < 4; ++m)
#pragma unroll
      for (int n = 0; n < NFR; ++n)
        acc[m][n] = __builtin_amdgcn_mfma_f32_16x16x32_bf16(af[m], bfr[n], acc[m][n], 0, 0, 0);
    __syncthreads();
  }

#pragma unroll
  for (int m = 0; m < 4; ++m)
#pragma unroll
    for (int n = 0; n < NFR; ++n){
      int row = m0 + wr * 64 + m * 16 + g * 4;
      int col = n0 + wc * (BN / 2) + n * 16 + c15;
      f32x4 v = acc[m][n];
      if (F32OUT){
        float* C = (float*)Cp;
#pragma unroll
        for (int r = 0; r < 4; ++r) C[(size_t)(row + r) * N + col] = v[r];
      } else {
        unsigned short* C = (unsigned short*)Cp;
#pragma unroll
        for (int r = 0; r < 4; ++r) C[(size_t)(row + r) * N + col] = f2bf(v[r]);
      }
    }
}

// ---------------- V transpose: v[s][h*128+d] (stride vstride) -> vt[h][d][s] ----------------
__global__ void transpose_v_kernel(const unsigned short* __restrict__ v, int vstride,
                                   unsigned short* __restrict__ vt){
  __shared__ unsigned short t[64][65];
  int h  = blockIdx.z;
  int d0 = blockIdx.y * 64;
  int s0 = blockIdx.x * 64;
  int c  = threadIdx.x & 63;
  int r0 = threadIdx.x >> 6;
#pragma unroll
  for (int r = r0; r < 64; r += 4) t[r][c] = v[(size_t)(s0 + r) * vstride + h * HD + d0 + c];
  __syncthreads();
#pragma unroll
  for (int r = r0; r < 64; r += 4) vt[(size_t)(h * HD + d0 + r) * SL + s0 + c] = t[c][r];
}

// ---------------- flash attention v3: 8 waves, KVBLK=128, gload_lds staging ----------------
// 512 thr = 4 heads x 2 row-groups of 16 q-rows (round-10 geometry, 16 waves/CU).
// KVBLK=128 halves the number of softmax/barrier/staging instances per kv-col.
// K/V staged via global_load_lds with PRE-SWIZZLED per-lane global source
// (linear LDS dest, slot ^= row&7) -> zero staging ds_writes, zero staging VGPRs.
// Wave-uniform frag skipping above the causal diagonal (stale LDS in skipped
// region is discarded by the mask ternary; all unmasked reads are staged).
__global__ __launch_bounds__(512, 4) void flash_attn_kernel(
  const unsigned short* __restrict__ Q,    // row stride QKVN
  const unsigned short* __restrict__ Kb,   // row stride QKVN
  const unsigned short* __restrict__ Vt,   // [kvh*128+d][SL]
  unsigned short* __restrict__ O)          // row stride HID
{
  __shared__ __align__(16) unsigned short Ks[128 * 128];   // rows=kv, 256B rows, swz
  __shared__ __align__(16) unsigned short Vs[128 * 128];   // rows=d,  256B rows, swz
  const int tid = threadIdx.x, lane = tid & 63, wid = tid >> 6;
  const int g = lane >> 4, c15 = lane & 15;
  const int kvh = blockIdx.x;
  const int yy = blockIdx.y;
  const int qb = (yy < 32) ? (63 - yy) : (yy - 32);   // heavy-first, pair-balanced
  const int h = kvh * 4 + (wid & 3);
  const int rg = wid >> 2;
  const int q0 = qb * 32;
  const int qg = q0 + rg * 16 + c15;       // this lane's q row
  const int qmax = q0 + rg * 16 + 15;      // wave's max q row

  // Q frags (B-operand): col=c15 -> q, k = kk*32 + g*8 + j
  short8 aq[4];
  {
    size_t qrow = (size_t)qg * QKVN + h * HD;
#pragma unroll
    for (int kk = 0; kk < 4; ++kk)
      aq[kk] = *(const short8*)(&Q[qrow + kk * 32 + g * 8]);
  }

  // staging source addressing: LDS dest row = chunk + (lane>>4), slot = lane&15;
  // global col pre-applies inverse swizzle slot ^ (row&7).
  const int srow4 = lane >> 4;                       // 0..3
  const int slotE = (lane & 15) ^ srow4;             // chunks with (start&7)==0
  const unsigned short* Kg0 = Kb + (size_t)kvh * HD;
  const unsigned short* Vg0 = Vt + (size_t)kvh * HD * SL;

  float m_i = -1e30f, l_i = 0.f;
  f32x4 oacc[8];
#pragma unroll
  for (int df = 0; df < 8; ++df) oacc[df] = (f32x4){0.f, 0.f, 0.f, 0.f};

  const float scl2 = 0.08838834764831845f * 1.4426950408889634f;  // 1/sqrt(128)*log2e
  const int nt = (q0 + 31) / 128 + 1;
  for (int kt = 0; kt < nt; ++kt){
    __syncthreads();                      // all reads of previous tile done
    // stage K (128x128) + V^T (128x128): 4 K + 4 V issues per wave, 4 rows each
#pragma unroll
    for (int j = 0; j < 4; ++j){
      const int rbase = wid * 16 + j * 4;            // chunk start (mult of 4)
      const int col = (slotE ^ ((j & 1) << 2)) * 8;  // (lane&15)^(row&7) elems
      const int row = rbase + srow4;
      gload_lds16(Kg0 + (size_t)(kt * 128 + row) * QKVN + col, &Ks[rbase * 128]);
      gload_lds16(Vg0 + (size_t)row * SL + kt * 128 + col,     &Vs[rbase * 128]);
    }
    __syncthreads();                      // drains vmcnt(0) -> tile resident

    // S^T = K Q : lane holds q=c15, kv = f*16 + g*4 + r  (f = 0..7)
    f32x4 sc[8];
    __builtin_amdgcn_s_setprio(1);
#pragma unroll
    for (int f = 0; f < 8; ++f){
      sc[f] = (f32x4){0.f, 0.f, 0.f, 0.f};
      if (kt * 128 + f * 16 <= qmax){     // wave-uniform diagonal skip
#pragma unroll
        for (int kk = 0; kk < 4; ++kk){
          short8 bk = *(const short8*)((const char*)Ks + (f * 16 + c15) * 256 +
                                       ((kk * 64 + g * 16) ^ ((c15 & 7) << 4)));
          sc[f] = __builtin_amdgcn_mfma_f32_16x16x32_bf16(bk, aq[kk], sc[f], 0, 0, 0);
        }
      }
    }
    __builtin_amdgcn_s_setprio(0);

    // mask + scale (exp2 domain)
    float p[8][4];
    if (kt * 128 + 127 <= q0 + rg * 16){  // wave-uniformly full tile
#pragma unroll
      for (int f = 0; f < 8; ++f)
#pragma unroll
        for (int r = 0; r < 4; ++r) p[f][r] = sc[f][r] * scl2;
    } else {
#pragma unroll
      for (int f = 0; f < 8; ++f)
#pragma unroll
        for (int r = 0; r < 4; ++r){
          int kvg = kt * 128 + f * 16 + g * 4 + r;
          p[f][r] = (kvg <= qg) ? sc[f][r] * scl2 : -1e30f;
        }
    }

    float pmax = p[0][0];
#pragma unroll
    for (int f = 0; f < 8; ++f)
#pragma unroll
      for (int r = 0; r < 4; ++r) pmax = fmaxf(pmax, p[f][r]);
    pmax = fmaxf(pmax, __shfl_xor(pmax, 16, 64));
    pmax = fmaxf(pmax, __shfl_xor(pmax, 32, 64));

    if (!__all(pmax - m_i <= 8.0f)){      // defer-max
      float mnew = fmaxf(m_i, pmax);
      float cf = exp2f(m_i - mnew);
      float cfr[4];
#pragma unroll
      for (int r = 0; r < 4; ++r) cfr[r] = __shfl(cf, (lane & 48) | (g * 4 + r), 64);
#pragma unroll
      for (int df = 0; df < 8; ++df)
#pragma unroll
        for (int r = 0; r < 4; ++r) oacc[df][r] *= cfr[r];
      l_i *= cf;
      m_i = mnew;
    }

    float lsum = 0.f;
#pragma unroll
    for (int f = 0; f < 8; ++f)
#pragma unroll
      for (int r = 0; r < 4; ++r){ float e = exp2f(p[f][r] - m_i); p[f][r] = e; lsum += e; }
    lsum += __shfl_xor(lsum, 16, 64);
    lsum += __shfl_xor(lsum, 32, 64);
    l_i += lsum;

    unsigned int pd[8][2];
#pragma unroll
    for (int f = 0; f < 8; ++f){
      pd[f][0] = cvtpk(p[f][0], p[f][1]);
      pd[f][1] = cvtpk(p[f][2], p[f][3]);
    }

    // PV: kv k-dim = kk*32 (kk = 0..3); diagonal skip per kk (wave-uniform)
    const int src0 = ((g & 1) << 5) | c15;
    const int src1 = src0 + 16;
    const bool hiF = (g >= 2);
#pragma unroll
    for (int kk = 0; kk < 4; ++kk){
      if (kt * 128 + kk * 32 <= qmax){
        union { unsigned int u[4]; short8 s8; } pa;
#pragma unroll
        for (int pr = 0; pr < 2; ++pr){
          unsigned int a0 = __shfl((int)pd[2 * kk + 0][pr], src0, 64);
          unsigned int b0 = __shfl((int)pd[2 * kk + 1][pr], src0, 64);
          unsigned int a1 = __shfl((int)pd[2 * kk + 0][pr], src1, 64);
          unsigned int b1 = __shfl((int)pd[2 * kk + 1][pr], src1, 64);
          pa.u[pr]     = hiF ? b0 : a0;
          pa.u[2 + pr] = hiF ? b1 : a1;
        }
        __builtin_amdgcn_s_setprio(1);
#pragma unroll
        for (int df = 0; df < 8; ++df){
          short8 bv = *(const short8*)((const char*)Vs + (df * 16 + c15) * 256 +
                                       ((kk * 64 + g * 16) ^ ((c15 & 7) << 4)));
          oacc[df] = __builtin_amdgcn_mfma_f32_16x16x32_bf16(pa.s8, bv, oacc[df], 0, 0, 0);
        }
        __builtin_amdgcn_s_setprio(0);
      }
    }
  }

  float lr[4];
#pragma unroll
  for (int r = 0; r < 4; ++r) lr[r] = __shfl(l_i, (lane & 48) | (g * 4 + r), 64);
#pragma unroll
  for (int df = 0; df < 8; ++df)
#pragma unroll
    for (int r = 0; r < 4; ++r){
      int row = q0 + rg * 16 + g * 4 + r;
      O[(size_t)row * HID + h * HD + df * 16 + c15] = f2bf(oacc[df][r] / lr[r]);
    }
}

extern "C" void kernel_launch(void* const* d_in, const int* in_sizes, int n_in,
                              void* d_out, int out_size, void* d_ws, size_t ws_size,
                              hipStream_t stream)
{
  const float* hs  = (const float*)d_in[0];
  const float* qw  = (const float*)d_in[1];
  const float* kw  = (const float*)d_in[2];
  const float* vw  = (const float*)d_in[3];
  const float* ow  = (const float*)d_in[4];
  const int*   pos = (const int*)d_in[5];

  char* w = (char*)d_ws;
  auto alloc = [&](size_t bytes){ char* p = w; w += (bytes + 255) & ~(size_t)255; return p; };
  unsigned short* xb   = (unsigned short*)alloc((size_t)SL * HID * 2);
  unsigned short* wqkv = (unsigned short*)alloc((size_t)QKVN * HID * 2);
  unsigned short* owb  = (unsigned short*)alloc((size_t)HID * HID * 2);
  unsigned short* qkv  = (unsigned short*)alloc((size_t)SL * QKVN * 2);
  unsigned short* vt   = (unsigned short*)alloc((size_t)SL * KVW * 2);
  unsigned short* ab   = (unsigned short*)alloc((size_t)SL * HID * 2);
  float2*         tab  = (float2*)alloc((size_t)SL * 64 * sizeof(float2));

  auto cast = [&](const float* s, unsigned short* d, long n){
    int n8 = (int)(n / 8);
    int blocks = (n8 + 255) / 256; if (blocks > 2048) blocks = 2048;
    cast_f32_bf16<<<blocks, 256, 0, stream>>>(s, (uint4*)d, n8);
  };
  cast(hs, xb, (long)SL * HID);
  cast(qw, wqkv,                              (long)HID * HID);
  cast(kw, wqkv + (size_t)HID * HID,          (long)KVW * HID);
  cast(vw, wqkv + (size_t)(HID + KVW) * HID,  (long)KVW * HID);
  cast(ow, owb,                               (long)HID * HID);

  rope_table_kernel<<<(SL * 64 + 255) / 256, 256, 0, stream>>>(pos, tab);

  // fused QKV projection: [2048][6144] = xb @ wqkv^T  (grid 48x16 = 768 = 3/CU)
  gemm_bt<128, false><<<dim3(QKVN / 128, SL / 128), 256, 0, stream>>>(xb, wqkv, qkv, SL, QKVN, HID);

  // RoPE on q+k heads (40 heads), vectorized 8 pairs/thread
  rope_apply_kernel<<<(SL * 40 * 8 + 255) / 256, 256, 0, stream>>>(qkv, tab, 40, QKVN);

  transpose_v_kernel<<<dim3(SL / 64, HD / 64, NKV), 256, 0, stream>>>(qkv + HID + KVW, QKVN, vt);

  // grid: 8 KV groups x 64 q-blocks of 32 rows; 512-thread blocks, KVBLK=128
  flash_attn_kernel<<<dim3(NKV, SL / 32), 512, 0, stream>>>(qkv, qkv + HID, vt, ab);

  // O projection: proven 128x128 engine (grid 32x16 = 512)
  gemm_bt<128, true><<<dim3(HID / 128, SL / 128), 256, 0, stream>>>(ab, owb, d_out, SL, HID, HID);
}

// Round 13
// 337.391 us; speedup vs baseline: 1.1750x; 1.1539x over previous
//
#include <hip/hip_runtime.h>
#include <hip/hip_bf16.h>

#define NH   32
#define NKV  8
#define HD   128
#define SL   2048
#define HID  4096
#define KVW  1024   // NKV*HD
#define QKVN 6144   // HID + 2*KVW

typedef __attribute__((ext_vector_type(8))) short short8;
typedef __attribute__((ext_vector_type(4))) float f32x4;

static __device__ __forceinline__ unsigned short f2bf(float f){
  union { float f; unsigned int i; } v; v.f = f;
  unsigned int r = v.i + 0x7FFFu + ((v.i >> 16) & 1u);
  return (unsigned short)(r >> 16);
}
static __device__ __forceinline__ float bf2f(unsigned short u){
  union { unsigned int i; float f; } v; v.i = ((unsigned int)u) << 16; return v.f;
}
static __device__ __forceinline__ unsigned int pack2(float lo, float hi){
  return (unsigned int)f2bf(lo) | ((unsigned int)f2bf(hi) << 16);
}
static __device__ __forceinline__ unsigned int cvtpk(float lo, float hi){
  unsigned int d;
  asm("v_cvt_pk_bf16_f32 %0, %1, %2" : "=v"(d) : "v"(lo), "v"(hi));
  return d;
}

// async global -> LDS, 16 B per lane. LDS dest is wave-uniform base + lane*16.
static __device__ __forceinline__ void gload_lds16(const void* g, void* l){
  __builtin_amdgcn_global_load_lds(
      (const __attribute__((address_space(1))) void*)g,
      (__attribute__((address_space(3))) void*)l,
      16, 0, 0);
}

// ---------------- merged fp32 -> bf16 cast over 5 segments (one launch) ----------------
struct CastSegs {
  const float* src[5];
  unsigned short* dst[5];
  int off[6];   // prefix sums in units of 8 elems
};
__global__ void cast_all(CastSegs cs, int total8){
  int stride = gridDim.x * blockDim.x;
  for (int i = blockIdx.x * blockDim.x + threadIdx.x; i < total8; i += stride){
    int s = 0;
#pragma unroll
    for (int t = 1; t < 5; ++t) s += (i >= cs.off[t]) ? 1 : 0;
    int j = i - cs.off[s];
    const float4* sp = (const float4*)cs.src[s];
    float4 a = sp[2*j + 0];
    float4 b = sp[2*j + 1];
    uint4 o;
    o.x = pack2(a.x, a.y); o.y = pack2(a.z, a.w);
    o.z = pack2(b.x, b.y); o.w = pack2(b.z, b.w);
    ((uint4*)cs.dst[s])[j] = o;
  }
}

// ---------------- RoPE cos/sin table ----------------
__global__ void rope_table_kernel(const int* __restrict__ pos, float2* __restrict__ tab){
  int i = blockIdx.x * blockDim.x + threadIdx.x;
  if (i >= SL * 64) return;
  int s = i >> 6, f = i & 63;
  float inv = expf(-((float)(2 * f) / 128.0f) * 9.210340371976184f);
  float ang = (float)pos[s] * inv;
  float sn, cs;
  sincosf(ang, &sn, &cs);
  tab[i] = make_float2(cs, sn);
}

// ---------------- in-place RoPE, vectorized: thread = 8 (f, f+64) pairs ----------------
__global__ void rope_apply_kernel(unsigned short* x, const float2* __restrict__ tab,
                                  int nheads, int rowstride){
  int i = blockIdx.x * blockDim.x + threadIdx.x;
  int total = SL * nheads * 8;
  if (i >= total) return;
  int fb = (i & 7) * 8;
  int t = i >> 3;
  int h = t % nheads;
  int s = t / nheads;
  size_t base = (size_t)s * rowstride + h * HD;
  short8 x1 = *(const short8*)&x[base + fb];
  short8 x2 = *(const short8*)&x[base + fb + 64];
  const float2* tb = &tab[s * 64 + fb];
  short8 o1, o2;
#pragma unroll
  for (int j = 0; j < 8; ++j){
    float2 cs = tb[j];
    float a = bf2f((unsigned short)x1[j]);
    float b = bf2f((unsigned short)x2[j]);
    o1[j] = (short)f2bf(a * cs.x - b * cs.y);
    o2[j] = (short)f2bf(b * cs.x + a * cs.y);
  }
  *(short8*)&x[base + fb]      = o1;
  *(short8*)&x[base + fb + 64] = o2;
}

// ========== bt-GEMM: C[M][N] = A[M][K] * B[N][K]^T (proven ~815-850 TF) ==========
template<int BN, bool F32OUT>
__global__ __launch_bounds__(256) void gemm_bt(
  const unsigned short* __restrict__ A,
  const unsigned short* __restrict__ B,
  void* __restrict__ Cp, int M, int N, int K)
{
  constexpr int NFR = BN / 32;
  __shared__ __align__(16) unsigned short As[2][128 * 32];
  __shared__ __align__(16) unsigned short Bs[2][BN * 32];
  const int tid = threadIdx.x;
  const int lane = tid & 63, wid = tid >> 6;
  const int g = lane >> 4, c15 = lane & 15;
  const int wr = wid >> 1, wc = wid & 1;

  const int gx = gridDim.x, gy = gridDim.y;
  const int nwg = gx * gy;
  const int lin = blockIdx.y * gx + blockIdx.x;
  int mb, nb;
  const int cpx = nwg >> 3;
  const int RN  = cpx >> 3;
  if (RN > 0 && (gy & 7) == 0 && (cpx & 7) == 0 && gx % RN == 0 && (8 % (gx / RN)) == 0){
    int xcd = lin & 7, j = lin >> 3;
    int nrc = gx / RN;
    int rr = xcd / nrc, rc = xcd % nrc;
    mb = rr * 8 + (j & 7);
    nb = rc * RN + (j >> 3);
  } else { mb = lin / gx; nb = lin % gx; }
  const int m0 = mb * 128, n0 = nb * BN;

  const int srowA = wid * 32 + (lane >> 2);
  const int srowB = wid * (BN / 4) + (lane >> 2);
  const int scol  = (lane & 3) * 8;
  const unsigned short* Ag = &A[(size_t)(m0 + srowA) * K + scol];
  const unsigned short* Bg = &B[(size_t)(n0 + srowB) * K + scol];
  const size_t K16 = (size_t)16 * K;

  f32x4 acc[4][NFR] = {};

  gload_lds16(Ag,       &As[0][wid * 1024]);
  gload_lds16(Ag + K16, &As[0][wid * 1024 + 512]);
#pragma unroll
  for (int q = 0; q < BN / 64; ++q)
    gload_lds16(Bg + q * K16, &Bs[0][wid * (BN / 4) * 32 + q * 512]);
  __syncthreads();

  const int nk = K >> 5;
  for (int t = 0; t < nk; ++t){
    const int cur = t & 1;
    if (t + 1 < nk){
      const unsigned short* a2 = Ag + (size_t)(t + 1) * 32;
      const unsigned short* b2 = Bg + (size_t)(t + 1) * 32;
      const int nb2 = cur ^ 1;
      gload_lds16(a2,       &As[nb2][wid * 1024]);
      gload_lds16(a2 + K16, &As[nb2][wid * 1024 + 512]);
#pragma unroll
      for (int q = 0; q < BN / 64; ++q)
        gload_lds16(b2 + q * K16, &Bs[nb2][wid * (BN / 4) * 32 + q * 512]);
    }
    short8 af[4], bfr[NFR];
#pragma unroll
    for (int m = 0; m < 4; ++m)
      af[m] = *(const short8*)(&As[cur][(wr * 64 + m * 16 + c15) * 32 + g * 8]);
#pragma unroll
    for (int n = 0; n < NFR; ++n)
      bfr[n] = *(const short8*)(&Bs[cur][(wc * (BN / 2) + n * 16 + c15) * 32 + g * 8]);
#pragma unroll
    for (int m = 0; m < 4; ++m)
#pragma unroll
      for (int n = 0; n < NFR; ++n)
        acc[m][n] = __builtin_amdgcn_mfma_f32_16x16x32_bf16(af[m], bfr[n], acc[m][n], 0, 0, 0);
    __syncthreads();
  }

#pragma unroll
  for (int m = 0; m < 4; ++m)
#pragma unroll
    for (int n = 0; n < NFR; ++n){
      int row = m0 + wr * 64 + m * 16 + g * 4;
      int col = n0 + wc * (BN / 2) + n * 16 + c15;
      f32x4 v = acc[m][n];
      if (F32OUT){
        float* C = (float*)Cp;
#pragma unroll
        for (int r = 0; r < 4; ++r) C[(size_t)(row + r) * N + col] = v[r];
      } else {
        unsigned short* C = (unsigned short*)Cp;
#pragma unroll
        for (int r = 0; r < 4; ++r) C[(size_t)(row + r) * N + col] = f2bf(v[r]);
      }
    }
}

// ---------------- V transpose: v[s][h*128+d] (stride vstride) -> vt[h][d][s] ----------------
__global__ void transpose_v_kernel(const unsigned short* __restrict__ v, int vstride,
                                   unsigned short* __restrict__ vt){
  __shared__ unsigned short t[64][65];
  int h  = blockIdx.z;
  int d0 = blockIdx.y * 64;
  int s0 = blockIdx.x * 64;
  int c  = threadIdx.x & 63;
  int r0 = threadIdx.x >> 6;
#pragma unroll
  for (int r = r0; r < 64; r += 4) t[r][c] = v[(size_t)(s0 + r) * vstride + h * HD + d0 + c];
  __syncthreads();
#pragma unroll
  for (int r = r0; r < 64; r += 4) vt[(size_t)(h * HD + d0 + r) * SL + s0 + c] = t[c][r];
}

// ---------------- flash attention (round-10 best: 8 waves, KVBLK=64, dbuf) ----------------
// + diagonal-tile wave-uniform frag skipping (QK f-frags and PV kk-frags fully
// above the causal diagonal are skipped; sc/pd are 0 there so results unchanged).
__global__ __launch_bounds__(512, 4) void flash_attn_kernel(
  const unsigned short* __restrict__ Q,    // row stride QKVN
  const unsigned short* __restrict__ Kb,   // row stride QKVN
  const unsigned short* __restrict__ Vt,   // [kvh*128+d][SL]
  unsigned short* __restrict__ O)          // row stride HID
{
  __shared__ __align__(16) unsigned short Ks[2][64 * 128];   // XOR-swizzled
  __shared__ __align__(16) unsigned short Vs[2][128 * 64];   // XOR-swizzled
  const int tid = threadIdx.x, lane = tid & 63, wid = tid >> 6;
  const int g = lane >> 4, c15 = lane & 15;
  const int kvh = blockIdx.x;
  const int yy = blockIdx.y;
  const int qb = (yy < 32) ? (63 - yy) : (yy - 32);   // heavy-first, pair-balanced
  const int h = kvh * 4 + (wid & 3);
  const int rg = wid >> 2;
  const int q0 = qb * 32;
  const int qg = q0 + rg * 16 + c15;       // this lane's q row
  const int qmax = q0 + rg * 16 + 15;      // wave's max q row (uniform)

  short8 aq[4];
  {
    size_t qrow = (size_t)qg * QKVN + h * HD;
#pragma unroll
    for (int kk = 0; kk < 4; ++kk)
      aq[kk] = *(const short8*)(&Q[qrow + kk * 32 + g * 8]);
  }

  const int krow = tid >> 3, kcol = (tid & 7) * 8;
  const int vrow = tid >> 2, vcol = (tid & 3) * 8;
  const unsigned short* Kgb = Kb + (size_t)kvh * HD;
  const unsigned short* Vgb = Vt + ((size_t)kvh * HD + vrow) * SL;

  auto loadKV = [&](int kt, uint4& a, uint4& b, uint4& c, uint4& d){
    const unsigned short* kg = Kgb + (size_t)(kt * 64 + krow) * QKVN + kcol;
    a = *(const uint4*)kg; b = *(const uint4*)(kg + 64);
    const unsigned short* vg = Vgb + kt * 64 + vcol;
    c = *(const uint4*)vg; d = *(const uint4*)(vg + 32);
  };
  auto writeKV = [&](int buf, uint4 a, uint4 b, uint4 c, uint4 d){
    *(uint4*)((char*)&Ks[buf][0] + krow * 256 + (( kcol * 2       ) ^ ((krow & 7) << 4))) = a;
    *(uint4*)((char*)&Ks[buf][0] + krow * 256 + (((kcol * 2) + 128) ^ ((krow & 7) << 4))) = b;
    *(uint4*)((char*)&Vs[buf][0] + vrow * 128 + (( vcol * 2       ) ^ ((vrow & 7) << 4))) = c;
    *(uint4*)((char*)&Vs[buf][0] + vrow * 128 + (((vcol * 2) +  64) ^ ((vrow & 7) << 4))) = d;
  };

  float m_i = -1e30f, l_i = 0.f;
  f32x4 oacc[8];
#pragma unroll
  for (int df = 0; df < 8; ++df) oacc[df] = (f32x4){0.f, 0.f, 0.f, 0.f};

  const float scl2 = 0.08838834764831845f * 1.4426950408889634f;  // 1/sqrt(128)*log2e
  const int nt = (q0 + 31) / 64 + 1;

  uint4 kr0, kr1, vr0, vr1;
  loadKV(0, kr0, kr1, vr0, vr1);
  writeKV(0, kr0, kr1, vr0, vr1);
  if (nt > 1) loadKV(1, kr0, kr1, vr0, vr1);
  __syncthreads();

  for (int kt = 0; kt < nt; ++kt){
    const int cur = kt & 1, nxt = cur ^ 1;
    if (kt + 1 < nt) writeKV(nxt, kr0, kr1, vr0, vr1);
    if (kt + 2 < nt) loadKV(kt + 2, kr0, kr1, vr0, vr1);

    // S^T = K Q : lane holds q=c15, kv = f*16 + g*4 + r
    f32x4 sc[4];
    __builtin_amdgcn_s_setprio(1);
#pragma unroll
    for (int f = 0; f < 4; ++f){
      sc[f] = (f32x4){0.f, 0.f, 0.f, 0.f};
      if (kt * 64 + f * 16 <= qmax){       // wave-uniform diagonal skip
#pragma unroll
        for (int kk = 0; kk < 4; ++kk){
          short8 bk = *(const short8*)((const char*)&Ks[cur][0] + (f * 16 + c15) * 256 +
                                       ((kk * 64 + g * 16) ^ ((c15 & 7) << 4)));
          sc[f] = __builtin_amdgcn_mfma_f32_16x16x32_bf16(bk, aq[kk], sc[f], 0, 0, 0);
        }
      }
    }
    __builtin_amdgcn_s_setprio(0);

    float p[4][4];
    if (kt * 64 + 63 <= q0 + rg * 16){     // wave-uniformly full tile
#pragma unroll
      for (int f = 0; f < 4; ++f)
#pragma unroll
        for (int r = 0; r < 4; ++r) p[f][r] = sc[f][r] * scl2;
    } else {
#pragma unroll
      for (int f = 0; f < 4; ++f)
#pragma unroll
        for (int r = 0; r < 4; ++r){
          int kvg = kt * 64 + f * 16 + g * 4 + r;
          p[f][r] = (kvg <= qg) ? sc[f][r] * scl2 : -1e30f;
        }
    }

    float pmax = p[0][0];
#pragma unroll
    for (int f = 0; f < 4; ++f)
#pragma unroll
      for (int r = 0; r < 4; ++r) pmax = fmaxf(pmax, p[f][r]);
    pmax = fmaxf(pmax, __shfl_xor(pmax, 16, 64));
    pmax = fmaxf(pmax, __shfl_xor(pmax, 32, 64));

    if (!__all(pmax - m_i <= 8.0f)){       // defer-max
      float mnew = fmaxf(m_i, pmax);
      float cf = exp2f(m_i - mnew);
      float cfr[4];
#pragma unroll
      for (int r = 0; r < 4; ++r) cfr[r] = __shfl(cf, (lane & 48) | (g * 4 + r), 64);
#pragma unroll
      for (int df = 0; df < 8; ++df)
#pragma unroll
        for (int r = 0; r < 4; ++r) oacc[df][r] *= cfr[r];
      l_i *= cf;
      m_i = mnew;
    }

    float lsum = 0.f;
#pragma unroll
    for (int f = 0; f < 4; ++f)
#pragma unroll
      for (int r = 0; r < 4; ++r){ float e = exp2f(p[f][r] - m_i); p[f][r] = e; lsum += e; }
    lsum += __shfl_xor(lsum, 16, 64);
    lsum += __shfl_xor(lsum, 32, 64);
    l_i += lsum;

    unsigned int pd[4][2];
#pragma unroll
    for (int f = 0; f < 4; ++f){
      pd[f][0] = cvtpk(p[f][0], p[f][1]);
      pd[f][1] = cvtpk(p[f][2], p[f][3]);
    }

    const int src0 = ((g & 1) << 5) | c15;
    const int src1 = src0 + 16;
    const bool hiF = (g >= 2);
#pragma unroll
    for (int kk = 0; kk < 2; ++kk){
      if (kt * 64 + kk * 32 <= qmax){      // wave-uniform diagonal skip (pd==0 above)
        union { unsigned int u[4]; short8 s8; } pa;
#pragma unroll
        for (int pr = 0; pr < 2; ++pr){
          unsigned int a0 = __shfl((int)pd[2 * kk + 0][pr], src0, 64);
          unsigned int b0 = __shfl((int)pd[2 * kk + 1][pr], src0, 64);
          unsigned int a1 = __shfl((int)pd[2 * kk + 0][pr], src1, 64);
          unsigned int b1 = __shfl((int)pd[2 * kk + 1][pr], src1, 64);
          pa.u[pr]     = hiF ? b0 : a0;
          pa.u[2 + pr] = hiF ? b1 : a1;
        }
        __builtin_amdgcn_s_setprio(1);
#pragma unroll
        for (int df = 0; df < 8; ++df){
          short8 bv = *(const short8*)((const char*)&Vs[cur][0] + (df * 16 + c15) * 128 +
                                       ((kk * 64 + g * 16) ^ ((c15 & 7) << 4)));
          oacc[df] = __builtin_amdgcn_mfma_f32_16x16x32_bf16(pa.s8, bv, oacc[df], 0, 0, 0);
        }
        __builtin_amdgcn_s_setprio(0);
      }
    }
    __syncthreads();   // publish buf[nxt], release buf[cur]
  }

  float lr[4];
#pragma unroll
  for (int r = 0; r < 4; ++r) lr[r] = __shfl(l_i, (lane & 48) | (g * 4 + r), 64);
#pragma unroll
  for (int df = 0; df < 8; ++df)
#pragma unroll
    for (int r = 0; r < 4; ++r){
      int row = q0 + rg * 16 + g * 4 + r;
      O[(size_t)row * HID + h * HD + df * 16 + c15] = f2bf(oacc[df][r] / lr[r]);
    }
}

extern "C" void kernel_launch(void* const* d_in, const int* in_sizes, int n_in,
                              void* d_out, int out_size, void* d_ws, size_t ws_size,
                              hipStream_t stream)
{
  const float* hs  = (const float*)d_in[0];
  const float* qw  = (const float*)d_in[1];
  const float* kw  = (const float*)d_in[2];
  const float* vw  = (const float*)d_in[3];
  const float* ow  = (const float*)d_in[4];
  const int*   pos = (const int*)d_in[5];

  char* w = (char*)d_ws;
  auto alloc = [&](size_t bytes){ char* p = w; w += (bytes + 255) & ~(size_t)255; return p; };
  unsigned short* xb   = (unsigned short*)alloc((size_t)SL * HID * 2);
  unsigned short* wqkv = (unsigned short*)alloc((size_t)QKVN * HID * 2);
  unsigned short* owb  = (unsigned short*)alloc((size_t)HID * HID * 2);
  unsigned short* qkv  = (unsigned short*)alloc((size_t)SL * QKVN * 2);
  unsigned short* vt   = (unsigned short*)alloc((size_t)SL * KVW * 2);
  unsigned short* ab   = (unsigned short*)alloc((size_t)SL * HID * 2);
  float2*         tab  = (float2*)alloc((size_t)SL * 64 * sizeof(float2));

  // one merged cast launch: hs->xb, qw/kw/vw->wqkv(concat), ow->owb
  CastSegs cs;
  cs.src[0] = hs;  cs.dst[0] = xb;
  cs.src[1] = qw;  cs.dst[1] = wqkv;
  cs.src[2] = kw;  cs.dst[2] = wqkv + (size_t)HID * HID;
  cs.src[3] = vw;  cs.dst[3] = wqkv + (size_t)(HID + KVW) * HID;
  cs.src[4] = ow;  cs.dst[4] = owb;
  int n8s[5] = { SL * HID / 8, HID * HID / 8, KVW * HID / 8, KVW * HID / 8, HID * HID / 8 };
  cs.off[0] = 0;
  for (int i = 0; i < 5; ++i) cs.off[i + 1] = cs.off[i] + n8s[i];
  int total8 = cs.off[5];
  cast_all<<<2048, 256, 0, stream>>>(cs, total8);

  rope_table_kernel<<<(SL * 64 + 255) / 256, 256, 0, stream>>>(pos, tab);

  // fused QKV projection: [2048][6144] = xb @ wqkv^T  (grid 48x16 = 768 = 3/CU)
  gemm_bt<128, false><<<dim3(QKVN / 128, SL / 128), 256, 0, stream>>>(xb, wqkv, qkv, SL, QKVN, HID);

  // RoPE on q+k heads (40 heads), vectorized 8 pairs/thread
  rope_apply_kernel<<<(SL * 40 * 8 + 255) / 256, 256, 0, stream>>>(qkv, tab, 40, QKVN);

  transpose_v_kernel<<<dim3(SL / 64, HD / 64, NKV), 256, 0, stream>>>(qkv + HID + KVW, QKVN, vt);

  // grid: 8 KV groups x 64 q-blocks of 32 rows; 512-thread blocks (8 waves)
  flash_attn_kernel<<<dim3(NKV, SL / 32), 512, 0, stream>>>(qkv, qkv + HID, vt, ab);

  // O projection: proven 128x128 engine (grid 32x16 = 512)
  gemm_bt<128, true><<<dim3(HID / 128, SL / 128), 256, 0, stream>>>(ab, owb, d_out, SL, HID, HID);
}